// Round 7
// baseline (324.249 us; speedup 1.0000x reference)
//
#include <hip/hip_runtime.h>

#define DEVI __device__ __forceinline__

typedef short short4_t __attribute__((ext_vector_type(4)));
typedef short short8_t __attribute__((ext_vector_type(8)));
typedef __bf16 bf16x8 __attribute__((ext_vector_type(8)));
typedef float f32x4 __attribute__((ext_vector_type(4)));

// float -> bf16 bits, round-to-nearest-even
DEVI short f2bf(float f) {
    union { float f; unsigned u; } v; v.f = f;
    unsigned r = (v.u + 0x7fffu + ((v.u >> 16) & 1u)) >> 16;
    return (short)r;
}

// pack two floats to packed bf16 (round-half-up): one add each + one v_perm
DEVI unsigned pack_ru(float a, float b) {
    union { float f; unsigned u; } x, y; x.f = a; y.f = b;
    return __builtin_amdgcn_perm(y.u + 0x8000u, x.u + 0x8000u, 0x07060302u);
}

// async global->LDS, 16B per lane; lds dest must be wave-uniform base (+lane*16 implicit)
DEVI void g2lds16(const short* g, short* l) {
    __builtin_amdgcn_global_load_lds(
        (const __attribute__((address_space(1))) void*)g,
        (__attribute__((address_space(3))) void*)l, 16, 0, 0);
}

// ---------------- convert q,k,v fp32 -> bf16 concatenated [12288,1024] ----------------
__global__ __launch_bounds__(256) void cvt3_kernel(const float* __restrict__ q,
                                                   const float* __restrict__ k,
                                                   const float* __restrict__ v,
                                                   short* __restrict__ X) {
    const size_t N1 = (size_t)4096 * 1024;
    size_t e = ((size_t)blockIdx.x * 256 + threadIdx.x) * 4;
    const float* src; size_t off;
    if (e < N1)            { src = q; off = e; }
    else if (e < 2 * N1)   { src = k; off = e - N1; }
    else                   { src = v; off = e - 2 * N1; }
    f32x4 f = *(const f32x4*)(src + off);
    short4_t o;
    o[0] = f2bf(f[0]); o[1] = f2bf(f[1]); o[2] = f2bf(f[2]); o[3] = f2bf(f[3]);
    *(short4_t*)(X + e) = o;
}

// ---------------- W [1024][1024] fp32 row-major [k][n] -> Wt bf16 [n][k] ----------------
__global__ __launch_bounds__(256) void transpose_w_kernel(const float* __restrict__ W,
                                                          short* __restrict__ Wt) {
    __shared__ short T[64][65];
    const int t = threadIdx.x;
    const int kt = blockIdx.x * 64, nt = blockIdx.y * 64;
#pragma unroll
    for (int r = 0; r < 4; ++r) {
        int kl = (t >> 4) + 16 * r;
        int n0 = (t & 15) * 4;
        f32x4 f = *(const f32x4*)(W + (size_t)(kt + kl) * 1024 + nt + n0);
#pragma unroll
        for (int j = 0; j < 4; ++j) T[n0 + j][kl] = f2bf(f[j]);
    }
    __syncthreads();
#pragma unroll
    for (int r = 0; r < 2; ++r) {
        int nl = (t >> 3) + 32 * r;
        int k0 = (t & 7) * 8;
        short8_t v;
#pragma unroll
        for (int j = 0; j < 8; ++j) v[j] = T[nl][k0 + j];
        *(short8_t*)(Wt + (size_t)(nt + nl) * 1024 + kt + k0) = v;
    }
}

// ---------------- GEMM 128x128  C[M][N] = A[M][K]*Bt[N][K]^T + bias ----------------
template <typename OutT>
__global__ __launch_bounds__(256) void gemm_bt_kernel(const short* __restrict__ A,
                                                      const short* __restrict__ Bt,
                                                      const float* __restrict__ bias,
                                                      OutT* __restrict__ C,
                                                      int M, int N, int K,
                                                      int qrows, float qscale) {
    __shared__ __align__(16) short As[128 * 32];
    __shared__ __align__(16) short Bs[128 * 32];
    const int tid  = threadIdx.x;
    const int lane = tid & 63, wave = tid >> 6;
    const int quad = lane >> 4, l16 = lane & 15;
    const int row0 = blockIdx.x * 128, col0 = blockIdx.y * 128;
    const int wm = (wave >> 1) * 64, wn = (wave & 1) * 64;
    const int srow = lane >> 2;
    const int scol = (lane & 3) * 8;
    f32x4 acc[4][4] = {};
    for (int k0 = 0; k0 < K; k0 += 32) {
#pragma unroll
        for (int r = 0; r < 2; ++r) {
            int rb = r * 64 + wave * 16;
            g2lds16(A  + (size_t)(row0 + rb + srow) * K + k0 + scol, &As[rb * 32]);
            g2lds16(Bt + (size_t)(col0 + rb + srow) * K + k0 + scol, &Bs[rb * 32]);
        }
        __syncthreads();
        bf16x8 af[4], bfr[4];
#pragma unroll
        for (int mi = 0; mi < 4; ++mi) af[mi]  = *(const bf16x8*)&As[(wm + mi * 16 + l16) * 32 + quad * 8];
#pragma unroll
        for (int ni = 0; ni < 4; ++ni) bfr[ni] = *(const bf16x8*)&Bs[(wn + ni * 16 + l16) * 32 + quad * 8];
#pragma unroll
        for (int mi = 0; mi < 4; ++mi)
#pragma unroll
            for (int ni = 0; ni < 4; ++ni)
                acc[mi][ni] = __builtin_amdgcn_mfma_f32_16x16x32_bf16(af[mi], bfr[ni], acc[mi][ni], 0, 0, 0);
        __syncthreads();
    }
#pragma unroll
    for (int mi = 0; mi < 4; ++mi) {
#pragma unroll
        for (int ni = 0; ni < 4; ++ni) {
            int col = col0 + wn + ni * 16 + l16;
            float bv = bias[col];
#pragma unroll
            for (int i = 0; i < 4; ++i) {
                int row = row0 + wm + mi * 16 + quad * 4 + i;
                float val = acc[mi][ni][i] + bv;
                if (row < qrows) val *= qscale;
                if constexpr (sizeof(OutT) == 2) C[(size_t)row * N + col] = (OutT)f2bf(val);
                else                             C[(size_t)row * N + col] = (OutT)val;
            }
        }
    }
}

// ---------------- GEMM 64x128 tiles (more blocks/CU for the small output GEMM) ----------------
__global__ __launch_bounds__(256) void gemm_bt64_kernel(const short* __restrict__ A,
                                                        const short* __restrict__ Bt,
                                                        const float* __restrict__ bias,
                                                        float* __restrict__ C,
                                                        int M, int N, int K) {
    __shared__ __align__(16) short As[64 * 32];
    __shared__ __align__(16) short Bs[128 * 32];
    const int tid  = threadIdx.x;
    const int lane = tid & 63, wave = tid >> 6;
    const int quad = lane >> 4, l16 = lane & 15;
    const int row0 = blockIdx.x * 64, col0 = blockIdx.y * 128;
    const int wn = wave * 32;
    const int srow = lane >> 2;
    const int scol = (lane & 3) * 8;
    f32x4 acc[4][2] = {};
    for (int k0 = 0; k0 < K; k0 += 32) {
        {
            int rb = wave * 16;
            g2lds16(A + (size_t)(row0 + rb + srow) * K + k0 + scol, &As[rb * 32]);
        }
#pragma unroll
        for (int r = 0; r < 2; ++r) {
            int rb = r * 64 + wave * 16;
            g2lds16(Bt + (size_t)(col0 + rb + srow) * K + k0 + scol, &Bs[rb * 32]);
        }
        __syncthreads();
        bf16x8 af[4], bfr[2];
#pragma unroll
        for (int mi = 0; mi < 4; ++mi) af[mi]  = *(const bf16x8*)&As[(mi * 16 + l16) * 32 + quad * 8];
#pragma unroll
        for (int ni = 0; ni < 2; ++ni) bfr[ni] = *(const bf16x8*)&Bs[(wn + ni * 16 + l16) * 32 + quad * 8];
#pragma unroll
        for (int mi = 0; mi < 4; ++mi)
#pragma unroll
            for (int ni = 0; ni < 2; ++ni)
                acc[mi][ni] = __builtin_amdgcn_mfma_f32_16x16x32_bf16(af[mi], bfr[ni], acc[mi][ni], 0, 0, 0);
        __syncthreads();
    }
#pragma unroll
    for (int mi = 0; mi < 4; ++mi) {
#pragma unroll
        for (int ni = 0; ni < 2; ++ni) {
            int col = col0 + wn + ni * 16 + l16;
            float bv = bias[col];
#pragma unroll
            for (int i = 0; i < 4; ++i) {
                int row = row0 + mi * 16 + quad * 4 + i;
                C[(size_t)row * N + col] = acc[mi][ni][i] + bv;
            }
        }
    }
}

// ---------------- P_v [b*2048+s][1024] head slice -> VT[(h*2+b)*64+d][2048] ----------------
__global__ __launch_bounds__(256) void transpose_v_kernel(const short* __restrict__ Pv,
                                                          short* __restrict__ VT) {
    __shared__ short T[64][65];
    const int t = threadIdx.x;
    const int hb = blockIdx.x, st = blockIdx.y * 64;
    const int h = hb >> 1, b = hb & 1;
#pragma unroll
    for (int r = 0; r < 2; ++r) {
        int sl = (t >> 3) + 32 * r;
        short8_t v = *(const short8_t*)(Pv + (size_t)(b * 2048 + st + sl) * 1024 + h * 64 + (t & 7) * 8);
#pragma unroll
        for (int j = 0; j < 8; ++j) T[(t & 7) * 8 + j][sl] = v[j];
    }
    __syncthreads();
#pragma unroll
    for (int r = 0; r < 2; ++r) {
        int dl = (t >> 3) + 32 * r;
        short8_t v;
#pragma unroll
        for (int j = 0; j < 8; ++j) v[j] = T[dl][(t & 7) * 8 + j];
        *(short8_t*)(VT + ((size_t)hb * 64 + dl) * 2048 + st + (t & 7) * 8) = v;
    }
}

// ---------------- flash attention v6: permuted K-tile -> full-rate K=32 PV ----------------
// 256 threads (4 waves x 64 q), 2 blocks/CU. P rows 0..4095 = Q proj (PRESCALED), 4096.. = K.
// K-tile LDS rows permuted within each 32-kv group: row r <-> kv (r>>2)*8+(r&3) (+4 for rows 16..31).
// Then the S^T C-frags of a chunk pair hold exactly kv=quad*8+{0..7} -> direct K=32 PV B-operand.
__global__ __launch_bounds__(256, 2) void attn_kernel(const short* __restrict__ P,
                                                      const short* __restrict__ VT,
                                                      short* __restrict__ O) {
    constexpr int LDK = 72;   // 144B rows: b128 frag reads conflict-free
    constexpr int LDV = 136;  // 272B rows: b128 frag reads conflict-free
    constexpr int LDO = 72;   // epilogue transpose stride
    union SmemU {
        struct { short Ks[2][128 * LDK]; short Vs[2][64 * LDV]; } s;
        short OT[256 * LDO];
    };
    __shared__ __align__(16) SmemU sm;

    const int t = threadIdx.x;
    const int lane = t & 63, wave = t >> 6;
    const int quad = lane >> 4, l16 = lane & 15;
    // XCD swizzle: 256 blocks, xcd = bx&7 -> each XCD owns 4 hb (K/V slices fit its L2)
    const int bx = blockIdx.x;
    const int xcd = bx & 7, bi = bx >> 3;
    const int hb = xcd * 4 + (bi & 3), qt = bi >> 2;   // hb 0..31, qt 0..7 (256-row q tiles)
    const int h = hb >> 1, b = hb & 1;
    const short* Pq  = P + (size_t)(b * 2048 + qt * 256) * 1024 + h * 64;
    const short* Pk  = P + (size_t)(4096 + b * 2048) * 1024 + h * 64;
    const short* VTh = VT + (size_t)hb * 64 * 2048;
    const int wq = wave * 64;

    // Q fragments: 64 q rows/wave, registers for the whole KV loop (B-operand layout)
    bf16x8 qf[4][2];
#pragma unroll
    for (int miq = 0; miq < 4; ++miq)
#pragma unroll
        for (int kh = 0; kh < 2; ++kh)
            qf[miq][kh] = *(const bf16x8*)(Pq + (size_t)(wq + miq * 16 + l16) * 1024 + kh * 32 + quad * 8);

    float lrow[4] = {0.f, 0.f, 0.f, 0.f};
    f32x4 oacc[4][4] = {};   // [di][miq], O^T C-layout: d=quad*4+i, q=l16

    // K staging: 32 rows/pass x 4; LDS row permuted within the 32-row group
    const int krow = t >> 3, kc8 = (t & 7) * 8;
    const int kj = krow & 7, kq = krow >> 3;
    const int lrow32 = (kj >= 4 ? 16 + (kj - 4) : kj) + kq * 4;   // permuted row within group
    // V staging: 16 rows/pass x 4 (kv-contiguous, unpermuted)
    const int vrow = t >> 4, vc8 = (t & 15) * 8;

    short8_t kreg[4], vreg[4];
#pragma unroll
    for (int it = 0; it < 4; ++it) {
        kreg[it] = *(const short8_t*)(Pk + (size_t)(it * 32 + krow) * 1024 + kc8);
        vreg[it] = *(const short8_t*)(VTh + (size_t)(it * 16 + vrow) * 2048 + vc8);
    }

    for (int tile = 0; tile < 16; ++tile) {
        const int buf = tile & 1;
        short* Ksb = sm.s.Ks[buf];
        short* Vsb = sm.s.Vs[buf];
#pragma unroll
        for (int it = 0; it < 4; ++it) {
            *(short8_t*)&Ksb[(it * 32 + lrow32) * LDK + kc8] = kreg[it];
            *(short8_t*)&Vsb[(it * 16 + vrow) * LDV + vc8] = vreg[it];
        }
        __syncthreads();
        if (tile + 1 < 16) {   // global prefetch overlaps the whole compute phase
            int kv0 = (tile + 1) * 128;
#pragma unroll
            for (int it = 0; it < 4; ++it) {
                kreg[it] = *(const short8_t*)(Pk + (size_t)(kv0 + it * 32 + krow) * 1024 + kc8);
                vreg[it] = *(const short8_t*)(VTh + (size_t)(it * 16 + vrow) * 2048 + kv0 + vc8);
            }
        }
#pragma unroll
        for (int p = 0; p < 4; ++p) {   // 4 pairs of 16-row chunks = 128 kv
            // K A-frags: chunkA rows p*32+l16, chunkB rows p*32+16+l16 (permuted kv space)
            bf16x8 aA0 = *(const bf16x8*)&Ksb[(p * 32 + l16) * LDK + quad * 8];
            bf16x8 aA1 = *(const bf16x8*)&Ksb[(p * 32 + l16) * LDK + 32 + quad * 8];
            bf16x8 aB0 = *(const bf16x8*)&Ksb[(p * 32 + 16 + l16) * LDK + quad * 8];
            bf16x8 aB1 = *(const bf16x8*)&Ksb[(p * 32 + 16 + l16) * LDK + 32 + quad * 8];
            // V A-frags for K=32 PV: lane d=l16, k(kv)=quad*8+j -> contiguous b128
            bf16x8 vA[4];
#pragma unroll
            for (int di = 0; di < 4; ++di)
                vA[di] = *(const bf16x8*)&Vsb[(di * 16 + l16) * LDV + p * 32 + quad * 8];
#pragma unroll
            for (int miq = 0; miq < 4; ++miq) {
                f32x4 sA = {}, sB = {};
                sA = __builtin_amdgcn_mfma_f32_16x16x32_bf16(aA0, qf[miq][0], sA, 0, 0, 0);
                sB = __builtin_amdgcn_mfma_f32_16x16x32_bf16(aB0, qf[miq][0], sB, 0, 0, 0);
                sA = __builtin_amdgcn_mfma_f32_16x16x32_bf16(aA1, qf[miq][1], sA, 0, 0, 0);
                sB = __builtin_amdgcn_mfma_f32_16x16x32_bf16(aB1, qf[miq][1], sB, 0, 0, 0);
                // exp2 (scale folded into Q); lane's 8 values = kv quad*8+{0..7} of this pair
                float eA0 = __builtin_amdgcn_exp2f(sA[0]);
                float eA1 = __builtin_amdgcn_exp2f(sA[1]);
                float eA2 = __builtin_amdgcn_exp2f(sA[2]);
                float eA3 = __builtin_amdgcn_exp2f(sA[3]);
                float eB0 = __builtin_amdgcn_exp2f(sB[0]);
                float eB1 = __builtin_amdgcn_exp2f(sB[1]);
                float eB2 = __builtin_amdgcn_exp2f(sB[2]);
                float eB3 = __builtin_amdgcn_exp2f(sB[3]);
                lrow[miq] += ((eA0 + eA1) + (eA2 + eA3)) + ((eB0 + eB1) + (eB2 + eB3));
                union { unsigned u[4]; bf16x8 b8; } pb;
                pb.u[0] = pack_ru(eA0, eA1);
                pb.u[1] = pack_ru(eA2, eA3);
                pb.u[2] = pack_ru(eB0, eB1);
                pb.u[3] = pack_ru(eB2, eB3);
                // O^T += V^T * P at K=32 (full rate)
#pragma unroll
                for (int di = 0; di < 4; ++di)
                    oacc[di][miq] = __builtin_amdgcn_mfma_f32_16x16x32_bf16(vA[di], pb.b8, oacc[di][miq], 0, 0, 0);
            }
        }
        __syncthreads();
    }

    // full row sums: reduce across quad bits (lane's lrow covers its quad's kv slots)
    float rinv[4];
#pragma unroll
    for (int miq = 0; miq < 4; ++miq) {
        float ls = lrow[miq];
        ls += __shfl_xor(ls, 16);
        ls += __shfl_xor(ls, 32);
        rinv[miq] = 1.0f / ls;   // aligned with O^T cols (q=l16)
    }
    // loop's final __syncthreads: all Ks/Vs reads done -> OT may alias them

    // O^T -> LDS (bf16), then coalesced row-major store
#pragma unroll
    for (int di = 0; di < 4; ++di) {
#pragma unroll
        for (int miq = 0; miq < 4; ++miq) {
            float v0 = oacc[di][miq][0] * rinv[miq];
            float v1 = oacc[di][miq][1] * rinv[miq];
            float v2 = oacc[di][miq][2] * rinv[miq];
            float v3 = oacc[di][miq][3] * rinv[miq];
            uint2 w;
            w.x = pack_ru(v0, v1);
            w.y = pack_ru(v2, v3);
            int q = wq + miq * 16 + l16;
            *(uint2*)&sm.OT[q * LDO + di * 16 + quad * 4] = w;
        }
    }
    __syncthreads();
    {
        short* dst = O + (size_t)(b * 2048 + qt * 256 + t) * 1024 + h * 64;
#pragma unroll
        for (int c = 0; c < 8; ++c)
            *(short8_t*)(dst + c * 8) = *(const short8_t*)&sm.OT[t * LDO + c * 8];
    }
}

extern "C" void kernel_launch(void* const* d_in, const int* in_sizes, int n_in,
                              void* d_out, int out_size, void* d_ws, size_t ws_size,
                              hipStream_t stream) {
    (void)in_sizes; (void)n_in; (void)out_size; (void)ws_size;
    const float* q  = (const float*)d_in[0];
    const float* k  = (const float*)d_in[1];
    const float* v  = (const float*)d_in[2];
    const float* Wq = (const float*)d_in[3];
    const float* bq = (const float*)d_in[4];
    const float* Wo = (const float*)d_in[5];
    const float* bo = (const float*)d_in[6];
    float* out = (float*)d_out;

    short* Xcat = (short*)d_ws;                        // [12288][1024] bf16
    short* WqT  = Xcat + (size_t)12288 * 1024;         // [1024][1024]
    short* WoT  = WqT + (size_t)1024 * 1024;           // [1024][1024]
    short* P    = WoT + (size_t)1024 * 1024;           // [12288][1024] (q|k|v projections)
    short* VT   = P + (size_t)12288 * 1024;            // [32][64][2048]
    short* O    = VT + (size_t)32 * 64 * 2048;         // [4096][1024]

    // softmax scale * log2(e), folded into Q rows of the projection GEMM
    const float qscale = 0.022097086912079608f * 1.4426950408889634f;

    cvt3_kernel<<<12288, 256, 0, stream>>>(q, k, v, Xcat);
    transpose_w_kernel<<<dim3(16, 16), 256, 0, stream>>>(Wq, WqT);
    transpose_w_kernel<<<dim3(16, 16), 256, 0, stream>>>(Wo, WoT);
    gemm_bt_kernel<short><<<dim3(96, 8), 256, 0, stream>>>(Xcat, WqT, bq, P, 12288, 1024, 1024, 4096, qscale);
    transpose_v_kernel<<<dim3(32, 32), 256, 0, stream>>>(P + (size_t)8192 * 1024, VT);
    attn_kernel<<<256, 256, 0, stream>>>(P, VT, O);
    gemm_bt64_kernel<<<dim3(64, 8), 256, 0, stream>>>(O, WoT, bo, out, 4096, 1024, 1024);
}

// Round 8
// 216.720 us; speedup vs baseline: 1.4962x; 1.4962x over previous
//
#include <hip/hip_runtime.h>

#define DEVI __device__ __forceinline__

typedef short short4_t __attribute__((ext_vector_type(4)));
typedef short short8_t __attribute__((ext_vector_type(8)));
typedef __bf16 bf16x8 __attribute__((ext_vector_type(8)));
typedef float f32x4 __attribute__((ext_vector_type(4)));

// float -> bf16 bits, round-to-nearest-even
DEVI short f2bf(float f) {
    union { float f; unsigned u; } v; v.f = f;
    unsigned r = (v.u + 0x7fffu + ((v.u >> 16) & 1u)) >> 16;
    return (short)r;
}

// pack two floats to packed bf16 (round-half-up): one add each + one v_perm
DEVI unsigned pack_ru(float a, float b) {
    union { float f; unsigned u; } x, y; x.f = a; y.f = b;
    return __builtin_amdgcn_perm(y.u + 0x8000u, x.u + 0x8000u, 0x07060302u);
}

// async global->LDS, 16B per lane; lds dest must be wave-uniform base (+lane*16 implicit)
DEVI void g2lds16(const short* g, short* l) {
    __builtin_amdgcn_global_load_lds(
        (const __attribute__((address_space(1))) void*)g,
        (__attribute__((address_space(3))) void*)l, 16, 0, 0);
}

// ---------------- convert q,k,v fp32 -> bf16 concatenated [12288,1024] ----------------
__global__ __launch_bounds__(256) void cvt3_kernel(const float* __restrict__ q,
                                                   const float* __restrict__ k,
                                                   const float* __restrict__ v,
                                                   short* __restrict__ X) {
    const size_t N1 = (size_t)4096 * 1024;
    size_t e = ((size_t)blockIdx.x * 256 + threadIdx.x) * 4;
    const float* src; size_t off;
    if (e < N1)            { src = q; off = e; }
    else if (e < 2 * N1)   { src = k; off = e - N1; }
    else                   { src = v; off = e - 2 * N1; }
    f32x4 f = *(const f32x4*)(src + off);
    short4_t o;
    o[0] = f2bf(f[0]); o[1] = f2bf(f[1]); o[2] = f2bf(f[2]); o[3] = f2bf(f[3]);
    *(short4_t*)(X + e) = o;
}

// ---------------- W [1024][1024] fp32 row-major [k][n] -> Wt bf16 [n][k] ----------------
__global__ __launch_bounds__(256) void transpose_w_kernel(const float* __restrict__ W,
                                                          short* __restrict__ Wt) {
    __shared__ short T[64][65];
    const int t = threadIdx.x;
    const int kt = blockIdx.x * 64, nt = blockIdx.y * 64;
#pragma unroll
    for (int r = 0; r < 4; ++r) {
        int kl = (t >> 4) + 16 * r;
        int n0 = (t & 15) * 4;
        f32x4 f = *(const f32x4*)(W + (size_t)(kt + kl) * 1024 + nt + n0);
#pragma unroll
        for (int j = 0; j < 4; ++j) T[n0 + j][kl] = f2bf(f[j]);
    }
    __syncthreads();
#pragma unroll
    for (int r = 0; r < 2; ++r) {
        int nl = (t >> 3) + 32 * r;
        int k0 = (t & 7) * 8;
        short8_t v;
#pragma unroll
        for (int j = 0; j < 8; ++j) v[j] = T[nl][k0 + j];
        *(short8_t*)(Wt + (size_t)(nt + nl) * 1024 + kt + k0) = v;
    }
}

// ---------------- GEMM 128x128  C[M][N] = A[M][K]*Bt[N][K]^T + bias ----------------
template <typename OutT>
__global__ __launch_bounds__(256) void gemm_bt_kernel(const short* __restrict__ A,
                                                      const short* __restrict__ Bt,
                                                      const float* __restrict__ bias,
                                                      OutT* __restrict__ C,
                                                      int M, int N, int K,
                                                      int qrows, float qscale) {
    __shared__ __align__(16) short As[128 * 32];
    __shared__ __align__(16) short Bs[128 * 32];
    const int tid  = threadIdx.x;
    const int lane = tid & 63, wave = tid >> 6;
    const int quad = lane >> 4, l16 = lane & 15;
    const int row0 = blockIdx.x * 128, col0 = blockIdx.y * 128;
    const int wm = (wave >> 1) * 64, wn = (wave & 1) * 64;
    const int srow = lane >> 2;
    const int scol = (lane & 3) * 8;
    f32x4 acc[4][4] = {};
    for (int k0 = 0; k0 < K; k0 += 32) {
#pragma unroll
        for (int r = 0; r < 2; ++r) {
            int rb = r * 64 + wave * 16;
            g2lds16(A  + (size_t)(row0 + rb + srow) * K + k0 + scol, &As[rb * 32]);
            g2lds16(Bt + (size_t)(col0 + rb + srow) * K + k0 + scol, &Bs[rb * 32]);
        }
        __syncthreads();
        bf16x8 af[4], bfr[4];
#pragma unroll
        for (int mi = 0; mi < 4; ++mi) af[mi]  = *(const bf16x8*)&As[(wm + mi * 16 + l16) * 32 + quad * 8];
#pragma unroll
        for (int ni = 0; ni < 4; ++ni) bfr[ni] = *(const bf16x8*)&Bs[(wn + ni * 16 + l16) * 32 + quad * 8];
#pragma unroll
        for (int mi = 0; mi < 4; ++mi)
#pragma unroll
            for (int ni = 0; ni < 4; ++ni)
                acc[mi][ni] = __builtin_amdgcn_mfma_f32_16x16x32_bf16(af[mi], bfr[ni], acc[mi][ni], 0, 0, 0);
        __syncthreads();
    }
#pragma unroll
    for (int mi = 0; mi < 4; ++mi) {
#pragma unroll
        for (int ni = 0; ni < 4; ++ni) {
            int col = col0 + wn + ni * 16 + l16;
            float bv = bias[col];
#pragma unroll
            for (int i = 0; i < 4; ++i) {
                int row = row0 + wm + mi * 16 + quad * 4 + i;
                float val = acc[mi][ni][i] + bv;
                if (row < qrows) val *= qscale;
                if constexpr (sizeof(OutT) == 2) C[(size_t)row * N + col] = (OutT)f2bf(val);
                else                             C[(size_t)row * N + col] = (OutT)val;
            }
        }
    }
}

// ---------------- GEMM 64x128 tiles (more blocks/CU for the small output GEMM) ----------------
__global__ __launch_bounds__(256) void gemm_bt64_kernel(const short* __restrict__ A,
                                                        const short* __restrict__ Bt,
                                                        const float* __restrict__ bias,
                                                        float* __restrict__ C,
                                                        int M, int N, int K) {
    __shared__ __align__(16) short As[64 * 32];
    __shared__ __align__(16) short Bs[128 * 32];
    const int tid  = threadIdx.x;
    const int lane = tid & 63, wave = tid >> 6;
    const int quad = lane >> 4, l16 = lane & 15;
    const int row0 = blockIdx.x * 64, col0 = blockIdx.y * 128;
    const int wn = wave * 32;
    const int srow = lane >> 2;
    const int scol = (lane & 3) * 8;
    f32x4 acc[4][2] = {};
    for (int k0 = 0; k0 < K; k0 += 32) {
        {
            int rb = wave * 16;
            g2lds16(A + (size_t)(row0 + rb + srow) * K + k0 + scol, &As[rb * 32]);
        }
#pragma unroll
        for (int r = 0; r < 2; ++r) {
            int rb = r * 64 + wave * 16;
            g2lds16(Bt + (size_t)(col0 + rb + srow) * K + k0 + scol, &Bs[rb * 32]);
        }
        __syncthreads();
        bf16x8 af[4], bfr[2];
#pragma unroll
        for (int mi = 0; mi < 4; ++mi) af[mi]  = *(const bf16x8*)&As[(mi * 16 + l16) * 32 + quad * 8];
#pragma unroll
        for (int ni = 0; ni < 2; ++ni) bfr[ni] = *(const bf16x8*)&Bs[(wn + ni * 16 + l16) * 32 + quad * 8];
#pragma unroll
        for (int mi = 0; mi < 4; ++mi)
#pragma unroll
            for (int ni = 0; ni < 2; ++ni)
                acc[mi][ni] = __builtin_amdgcn_mfma_f32_16x16x32_bf16(af[mi], bfr[ni], acc[mi][ni], 0, 0, 0);
        __syncthreads();
    }
#pragma unroll
    for (int mi = 0; mi < 4; ++mi) {
#pragma unroll
        for (int ni = 0; ni < 2; ++ni) {
            int col = col0 + wn + ni * 16 + l16;
            float bv = bias[col];
#pragma unroll
            for (int i = 0; i < 4; ++i) {
                int row = row0 + mi * 16 + quad * 4 + i;
                C[(size_t)row * N + col] = acc[mi][ni][i] + bv;
            }
        }
    }
}

// ---------------- P_v [b*2048+s][1024] head slice -> VT[(h*2+b)*64+d][2048] ----------------
__global__ __launch_bounds__(256) void transpose_v_kernel(const short* __restrict__ Pv,
                                                          short* __restrict__ VT) {
    __shared__ short T[64][65];
    const int t = threadIdx.x;
    const int hb = blockIdx.x, st = blockIdx.y * 64;
    const int h = hb >> 1, b = hb & 1;
#pragma unroll
    for (int r = 0; r < 2; ++r) {
        int sl = (t >> 3) + 32 * r;
        short8_t v = *(const short8_t*)(Pv + (size_t)(b * 2048 + st + sl) * 1024 + h * 64 + (t & 7) * 8);
#pragma unroll
        for (int j = 0; j < 8; ++j) T[(t & 7) * 8 + j][sl] = v[j];
    }
    __syncthreads();
#pragma unroll
    for (int r = 0; r < 2; ++r) {
        int dl = (t >> 3) + 32 * r;
        short8_t v;
#pragma unroll
        for (int j = 0; j < 8; ++j) v[j] = T[dl][(t & 7) * 8 + j];
        *(short8_t*)(VT + ((size_t)hb * 64 + dl) * 2048 + st + (t & 7) * 8) = v;
    }
}

// ---------------- flash attention v7: permuted-K full-rate K=32 PV, miq=2, 2 blocks/CU ----------------
// 256 threads (4 waves x 32 q = q-tile 128), grid 512 -> true 2 blocks/CU (regs fit this time).
// P rows 0..4095 = Q proj (PRESCALED by inv_scale*log2e), 4096..8191 = K proj.
// K-tile LDS rows permuted within each 32-kv group: staged row lrow32 = (kj>=4?16+kj-4:kj)+kq*4
// so the S^T C-frags of a 16-row chunk pair hold exactly kv=quad*8+{0..7} -> direct K=32 PV B-operand.
__global__ __launch_bounds__(256, 2) void attn_kernel(const short* __restrict__ P,
                                                      const short* __restrict__ VT,
                                                      short* __restrict__ O) {
    constexpr int LDK = 72;   // 144B rows: b128 frag reads conflict-free
    constexpr int LDV = 136;  // 272B rows: b128 frag reads conflict-free
    constexpr int LDO = 72;   // epilogue transpose stride
    union SmemU {
        struct { short Ks[2][128 * LDK]; short Vs[2][64 * LDV]; } s;
        short OT[128 * LDO];
    };
    __shared__ __align__(16) SmemU sm;

    const int t = threadIdx.x;
    const int lane = t & 63, wave = t >> 6;
    const int quad = lane >> 4, l16 = lane & 15;
    // XCD swizzle: 512 blocks, xcd = bx&7 -> each XCD owns 4 hb (K/V slices fit its L2)
    const int bx = blockIdx.x;
    const int xcd = bx & 7, bi = bx >> 3;
    const int hb = xcd * 4 + (bi & 3), qt = bi >> 2;   // hb 0..31, qt 0..15 (128-row q tiles)
    const int h = hb >> 1, b = hb & 1;
    const short* Pq  = P + (size_t)(b * 2048 + qt * 128) * 1024 + h * 64;
    const short* Pk  = P + (size_t)(4096 + b * 2048) * 1024 + h * 64;
    const short* VTh = VT + (size_t)hb * 64 * 2048;
    const int wq = wave * 32;   // 32 q rows per wave

    // Q fragments: registers for the whole KV loop (B-operand layout = Q rows)
    bf16x8 qf[2][2];
#pragma unroll
    for (int miq = 0; miq < 2; ++miq)
#pragma unroll
        for (int kh = 0; kh < 2; ++kh)
            qf[miq][kh] = *(const bf16x8*)(Pq + (size_t)(wq + miq * 16 + l16) * 1024 + kh * 32 + quad * 8);

    float lrow[2] = {0.f, 0.f};
    f32x4 oacc[4][2] = {};   // [di][miq], O^T C-layout: d=quad*4+i, q=l16

    // K staging: 32 rows/pass x 4; LDS row permuted within the 32-row group
    const int krow = t >> 3, kc8 = (t & 7) * 8;
    const int kj = krow & 7, kq = krow >> 3;
    const int lrow32 = (kj >= 4 ? 16 + (kj - 4) : kj) + kq * 4;   // permuted row within group
    // V staging: 16 rows/pass x 4 (kv-contiguous, unpermuted)
    const int vrow = t >> 4, vc8 = (t & 15) * 8;

    short8_t kreg[4], vreg[4];
#pragma unroll
    for (int it = 0; it < 4; ++it) {
        kreg[it] = *(const short8_t*)(Pk + (size_t)(it * 32 + krow) * 1024 + kc8);
        vreg[it] = *(const short8_t*)(VTh + (size_t)(it * 16 + vrow) * 2048 + vc8);
    }

    for (int tile = 0; tile < 16; ++tile) {
        const int buf = tile & 1;
        short* Ksb = sm.s.Ks[buf];
        short* Vsb = sm.s.Vs[buf];
#pragma unroll
        for (int it = 0; it < 4; ++it) {
            *(short8_t*)&Ksb[(it * 32 + lrow32) * LDK + kc8] = kreg[it];
            *(short8_t*)&Vsb[(it * 16 + vrow) * LDV + vc8] = vreg[it];
        }
        __syncthreads();
        if (tile + 1 < 16) {   // global prefetch overlaps the whole compute phase
            int kv0 = (tile + 1) * 128;
#pragma unroll
            for (int it = 0; it < 4; ++it) {
                kreg[it] = *(const short8_t*)(Pk + (size_t)(kv0 + it * 32 + krow) * 1024 + kc8);
                vreg[it] = *(const short8_t*)(VTh + (size_t)(it * 16 + vrow) * 2048 + kv0 + vc8);
            }
        }
#pragma unroll
        for (int p = 0; p < 4; ++p) {   // 4 pairs of 16-row chunks = 128 kv
            // K A-frags: chunkA rows p*32+l16, chunkB rows p*32+16+l16 (permuted kv space)
            bf16x8 aA0 = *(const bf16x8*)&Ksb[(p * 32 + l16) * LDK + quad * 8];
            bf16x8 aA1 = *(const bf16x8*)&Ksb[(p * 32 + l16) * LDK + 32 + quad * 8];
            bf16x8 aB0 = *(const bf16x8*)&Ksb[(p * 32 + 16 + l16) * LDK + quad * 8];
            bf16x8 aB1 = *(const bf16x8*)&Ksb[(p * 32 + 16 + l16) * LDK + 32 + quad * 8];
            // V A-frags for K=32 PV: lane d=l16, k(kv)=quad*8+j -> contiguous b128
            bf16x8 vA[4];
#pragma unroll
            for (int di = 0; di < 4; ++di)
                vA[di] = *(const bf16x8*)&Vsb[(di * 16 + l16) * LDV + p * 32 + quad * 8];
#pragma unroll
            for (int miq = 0; miq < 2; ++miq) {
                f32x4 sA = {}, sB = {};
                sA = __builtin_amdgcn_mfma_f32_16x16x32_bf16(aA0, qf[miq][0], sA, 0, 0, 0);
                sB = __builtin_amdgcn_mfma_f32_16x16x32_bf16(aB0, qf[miq][0], sB, 0, 0, 0);
                sA = __builtin_amdgcn_mfma_f32_16x16x32_bf16(aA1, qf[miq][1], sA, 0, 0, 0);
                sB = __builtin_amdgcn_mfma_f32_16x16x32_bf16(aB1, qf[miq][1], sB, 0, 0, 0);
                // exp2 (scale folded into Q); lane's 8 values = kv quad*8+{0..7} of this pair
                float eA0 = __builtin_amdgcn_exp2f(sA[0]);
                float eA1 = __builtin_amdgcn_exp2f(sA[1]);
                float eA2 = __builtin_amdgcn_exp2f(sA[2]);
                float eA3 = __builtin_amdgcn_exp2f(sA[3]);
                float eB0 = __builtin_amdgcn_exp2f(sB[0]);
                float eB1 = __builtin_amdgcn_exp2f(sB[1]);
                float eB2 = __builtin_amdgcn_exp2f(sB[2]);
                float eB3 = __builtin_amdgcn_exp2f(sB[3]);
                lrow[miq] += ((eA0 + eA1) + (eA2 + eA3)) + ((eB0 + eB1) + (eB2 + eB3));
                union { unsigned u[4]; bf16x8 b8; } pb;
                pb.u[0] = pack_ru(eA0, eA1);
                pb.u[1] = pack_ru(eA2, eA3);
                pb.u[2] = pack_ru(eB0, eB1);
                pb.u[3] = pack_ru(eB2, eB3);
                // O^T += V^T * P at K=32 (full rate)
#pragma unroll
                for (int di = 0; di < 4; ++di)
                    oacc[di][miq] = __builtin_amdgcn_mfma_f32_16x16x32_bf16(vA[di], pb.b8, oacc[di][miq], 0, 0, 0);
            }
        }
        __syncthreads();
    }

    // full row sums: reduce across quad bits (lane's lrow covers its quad's kv slots)
    float rinv[2];
#pragma unroll
    for (int miq = 0; miq < 2; ++miq) {
        float ls = lrow[miq];
        ls += __shfl_xor(ls, 16);
        ls += __shfl_xor(ls, 32);
        rinv[miq] = 1.0f / ls;   // aligned with O^T cols (q=l16)
    }
    // loop's final __syncthreads: all Ks/Vs reads done -> OT may alias them

    // O^T -> LDS (bf16), then coalesced row-major store
#pragma unroll
    for (int di = 0; di < 4; ++di) {
#pragma unroll
        for (int miq = 0; miq < 2; ++miq) {
            float v0 = oacc[di][miq][0] * rinv[miq];
            float v1 = oacc[di][miq][1] * rinv[miq];
            float v2 = oacc[di][miq][2] * rinv[miq];
            float v3 = oacc[di][miq][3] * rinv[miq];
            uint2 w;
            w.x = pack_ru(v0, v1);
            w.y = pack_ru(v2, v3);
            int q = wq + miq * 16 + l16;
            *(uint2*)&sm.OT[q * LDO + di * 16 + quad * 4] = w;
        }
    }
    __syncthreads();
    {
        const int orow = t >> 1, ocol = (t & 1) * 32;
        short* dst = O + (size_t)(b * 2048 + qt * 128 + orow) * 1024 + h * 64 + ocol;
#pragma unroll
        for (int c = 0; c < 4; ++c)
            *(short8_t*)(dst + c * 8) = *(const short8_t*)&sm.OT[orow * LDO + ocol + c * 8];
    }
}

extern "C" void kernel_launch(void* const* d_in, const int* in_sizes, int n_in,
                              void* d_out, int out_size, void* d_ws, size_t ws_size,
                              hipStream_t stream) {
    (void)in_sizes; (void)n_in; (void)out_size; (void)ws_size;
    const float* q  = (const float*)d_in[0];
    const float* k  = (const float*)d_in[1];
    const float* v  = (const float*)d_in[2];
    const float* Wq = (const float*)d_in[3];
    const float* bq = (const float*)d_in[4];
    const float* Wo = (const float*)d_in[5];
    const float* bo = (const float*)d_in[6];
    float* out = (float*)d_out;

    short* Xcat = (short*)d_ws;                        // [12288][1024] bf16
    short* WqT  = Xcat + (size_t)12288 * 1024;         // [1024][1024]
    short* WoT  = WqT + (size_t)1024 * 1024;           // [1024][1024]
    short* P    = WoT + (size_t)1024 * 1024;           // [12288][1024] (q|k|v projections)
    short* VT   = P + (size_t)12288 * 1024;            // [32][64][2048]
    short* O    = VT + (size_t)32 * 64 * 2048;         // [4096][1024]

    // softmax scale * log2(e), folded into Q rows of the projection GEMM
    const float qscale = 0.022097086912079608f * 1.4426950408889634f;

    cvt3_kernel<<<12288, 256, 0, stream>>>(q, k, v, Xcat);
    transpose_w_kernel<<<dim3(16, 16), 256, 0, stream>>>(Wq, WqT);
    transpose_w_kernel<<<dim3(16, 16), 256, 0, stream>>>(Wo, WoT);
    gemm_bt_kernel<short><<<dim3(96, 8), 256, 0, stream>>>(Xcat, WqT, bq, P, 12288, 1024, 1024, 4096, qscale);
    transpose_v_kernel<<<dim3(32, 32), 256, 0, stream>>>(P + (size_t)8192 * 1024, VT);
    attn_kernel<<<512, 256, 0, stream>>>(P, VT, O);
    gemm_bt64_kernel<<<dim3(64, 8), 256, 0, stream>>>(O, WoT, bo, out, 4096, 1024, 1024);
}